// Round 1
// baseline (384.717 us; speedup 1.0000x reference)
//
#include <hip/hip_runtime.h>
#include <hip/hip_bf16.h>
#include <cstdint>
#include <cstddef>

typedef unsigned short u16;
typedef __bf16 bf16x8 __attribute__((ext_vector_type(8)));
typedef float f32x4 __attribute__((ext_vector_type(4)));
typedef u16 u16x8 __attribute__((ext_vector_type(8)));

#define NROWS 15360   // B*C = 512*30
#define KDIM 512
#define BDIM 512
#define CDIM 30
#define TDIM 3
#define EDIM 6

__device__ __forceinline__ float bf2f(u16 u) {
  union { unsigned i; float f; } v; v.i = ((unsigned)u) << 16; return v.f;
}
__device__ __forceinline__ u16 f2bf(float f) {
  union { float f; unsigned i; } v; v.f = f;
  unsigned r = v.i + 0x7fffu + ((v.i >> 16) & 1u);
  return (u16)(r >> 16);
}

// ---------------- convert fp32 -> bf16 (vectorized) ----------------
__global__ __launch_bounds__(256) void cvt_bf16_kernel(const float* __restrict__ x,
                                                       u16* __restrict__ o, int n) {
  int i = (blockIdx.x * 256 + threadIdx.x) * 8;
  if (i + 8 > n) return;
  float4 a = *(const float4*)(x + i);
  float4 b = *(const float4*)(x + i + 4);
  u16x8 v;
  v[0] = f2bf(a.x); v[1] = f2bf(a.y); v[2] = f2bf(a.z); v[3] = f2bf(a.w);
  v[4] = f2bf(b.x); v[5] = f2bf(b.y); v[6] = f2bf(b.z); v[7] = f2bf(b.w);
  *(u16x8*)(o + i) = v;
}

// ---------------- transpose 512x512 fp32 -> bf16 [N][K] ----------------
// blockIdx.y = matrix id 0..16: 0 fc1, 1 fc2, 2..7 ew1, 8..13 ew2, 14..16 tw1
__global__ __launch_bounds__(256) void transpose_w_kernel(
    const float* __restrict__ fc1, const float* __restrict__ fc2,
    const float* __restrict__ ew1, const float* __restrict__ ew2,
    const float* __restrict__ tw1, u16* __restrict__ wt) {
  int mid = blockIdx.y;
  const float* src;
  if (mid == 0) src = fc1;
  else if (mid == 1) src = fc2;
  else if (mid < 8) src = ew1 + (size_t)(mid - 2) * 262144;
  else if (mid < 14) src = ew2 + (size_t)(mid - 8) * 262144;
  else src = tw1 + (size_t)(mid - 14) * 262144;
  u16* dst = wt + (size_t)mid * 262144;

  int tile = blockIdx.x;
  int tr = (tile >> 3) * 64, tc = (tile & 7) * 64;
  __shared__ float t[64][65];
  int c = threadIdx.x & 63, r0 = threadIdx.x >> 6;
#pragma unroll
  for (int i = 0; i < 16; i++) {
    int r = r0 + i * 4;
    t[r][c] = src[(size_t)(tr + r) * 512 + tc + c];
  }
  __syncthreads();
#pragma unroll
  for (int i = 0; i < 16; i++) {
    int r = r0 + i * 4;
    dst[(size_t)(tc + r) * 512 + tr + c] = f2bf(t[c][r]);
  }
}

// ---------------- bf16 MFMA GEMM:  C[M x 512] = A[M x 512] @ B  (BT = B^T [512][512]) ----
// 128x128 tile, 256 threads = 4 waves (2x2), each wave 64x64 = 4x4 mfma frags.
// LDS pad: row stride 40 ushorts (80B) -> 2-way max bank conflict on ds_read_b128.
template <int RELU>
__global__ __launch_bounds__(256, 2) void gemm_bt(
    const u16* __restrict__ A, const u16* __restrict__ BT,
    const float* __restrict__ bias, u16* __restrict__ C, int ldc) {
  __shared__ u16 Al[128 * 40];
  __shared__ u16 Bl[128 * 40];
  const int K = KDIM;
  int tid = threadIdx.x, lane = tid & 63, w = tid >> 6;
  int wr = w >> 1, wc = w & 1;
  int brow = blockIdx.x * 128, bcol = blockIdx.y * 128;

  int srow = tid >> 2;          // 0..63
  int skc = (tid & 3) * 8;      // 0,8,16,24
  const u16* Ag = A + (size_t)(brow + srow) * K + skc;
  const u16* Bg = BT + (size_t)(bcol + srow) * K + skc;

  u16x8 ra0, ra1, rb0, rb1;
  ra0 = *(const u16x8*)(Ag);
  ra1 = *(const u16x8*)(Ag + 64 * K);
  rb0 = *(const u16x8*)(Bg);
  rb1 = *(const u16x8*)(Bg + 64 * K);

  f32x4 zero; zero[0] = 0.f; zero[1] = 0.f; zero[2] = 0.f; zero[3] = 0.f;
  f32x4 acc[4][4];
#pragma unroll
  for (int m = 0; m < 4; m++)
#pragma unroll
    for (int n = 0; n < 4; n++) acc[m][n] = zero;

  int koff = (lane >> 4) * 8;
  int rbase = wr * 64 + (lane & 15);
  int cbase = wc * 64 + (lane & 15);

  for (int kt = 0; kt < 16; ++kt) {
    *(u16x8*)&Al[srow * 40 + skc] = ra0;
    *(u16x8*)&Al[(srow + 64) * 40 + skc] = ra1;
    *(u16x8*)&Bl[srow * 40 + skc] = rb0;
    *(u16x8*)&Bl[(srow + 64) * 40 + skc] = rb1;
    __syncthreads();
    if (kt < 15) {
      int ko = (kt + 1) * 32;
      ra0 = *(const u16x8*)(Ag + ko);
      ra1 = *(const u16x8*)(Ag + 64 * K + ko);
      rb0 = *(const u16x8*)(Bg + ko);
      rb1 = *(const u16x8*)(Bg + 64 * K + ko);
    }
    bf16x8 af[4], bfr[4];
#pragma unroll
    for (int m = 0; m < 4; m++) af[m] = *(const bf16x8*)&Al[(rbase + m * 16) * 40 + koff];
#pragma unroll
    for (int n = 0; n < 4; n++) bfr[n] = *(const bf16x8*)&Bl[(cbase + n * 16) * 40 + koff];
#pragma unroll
    for (int m = 0; m < 4; m++)
#pragma unroll
      for (int n = 0; n < 4; n++)
        acc[m][n] = __builtin_amdgcn_mfma_f32_16x16x32_bf16(af[m], bfr[n], acc[m][n], 0, 0, 0);
    __syncthreads();
  }

  // epilogue: bias + optional relu, bf16 store
  int col0 = bcol + wc * 64 + (lane & 15);
  int row0 = brow + wr * 64 + (lane >> 4) * 4;
#pragma unroll
  for (int n = 0; n < 4; n++) {
    int col = col0 + n * 16;
    float bv = bias[col - bcol + (bcol)];  // bias indexed by global col (N==512)
#pragma unroll
    for (int m = 0; m < 4; m++) {
      int row = row0 + m * 16;
#pragma unroll
      for (int r = 0; r < 4; r++) {
        float v = acc[m][n][r] + bv;
        if (RELU) v = fmaxf(v, 0.f);
        C[(size_t)(row + r) * ldc + col] = f2bf(v);
      }
    }
  }
}

// ---------------- gate: glog = h @ w_gate[t] -> top3 softmax -> gates [B][T][C][E] ----
__global__ __launch_bounds__(256) void gate_kernel(const u16* __restrict__ h,
                                                   const float* __restrict__ wg,
                                                   float* __restrict__ gates) {
  __shared__ float wgl[TDIM * 512 * EDIM];  // 36 KB
  for (int i = threadIdx.x; i < TDIM * 512 * EDIM; i += 256) wgl[i] = wg[i];
  __syncthreads();
  int w = threadIdx.x >> 6, lane = threadIdx.x & 63;
  for (int r = blockIdx.x * 4 + w; r < NROWS; r += gridDim.x * 4) {
    float acc[18];
#pragma unroll
    for (int i = 0; i < 18; i++) acc[i] = 0.f;
#pragma unroll
    for (int j = 0; j < 8; j++) {
      int k = j * 64 + lane;
      float hv = bf2f(h[(size_t)r * 512 + k]);
#pragma unroll
      for (int t = 0; t < 3; t++)
#pragma unroll
        for (int e = 0; e < 6; e++)
          acc[t * 6 + e] += hv * wgl[(t * 512 + k) * 6 + e];
    }
#pragma unroll
    for (int i = 0; i < 18; i++) {
      float v = acc[i];
      for (int off = 32; off; off >>= 1) v += __shfl_xor(v, off, 64);
      acc[i] = v;
    }
    if (lane == 0) {
      int b = r / CDIM, c = r % CDIM;
      for (int t = 0; t < 3; t++) {
        float g[6];
        for (int e = 0; e < 6; e++) g[e] = acc[t * 6 + e];
        float out[6] = {0, 0, 0, 0, 0, 0};
        int idx[3]; float val[3];
        unsigned used = 0;
        for (int kk = 0; kk < 3; kk++) {
          int best = 0; float bv = -1e30f;
          for (int e = 0; e < 6; e++)
            if (!((used >> e) & 1) && g[e] > bv) { bv = g[e]; best = e; }
          used |= 1u << best; idx[kk] = best; val[kk] = bv;
        }
        float mx = val[0];
        float s = 0.f, ex[3];
        for (int kk = 0; kk < 3; kk++) { ex[kk] = expf(val[kk] - mx); s += ex[kk]; }
        for (int kk = 0; kk < 3; kk++) out[idx[kk]] = ex[kk] / s;
        float* gp = &gates[(size_t)((b * TDIM + t) * CDIM + c) * EDIM];
        for (int e = 0; e < 6; e++) gp[e] = out[e];
      }
    }
  }
}

// ---------------- combine: y[t][r][:] = sum_e gates[b,t,c,e] * eo[r][e][:] ----------------
__global__ __launch_bounds__(256) void combine_kernel(const u16* __restrict__ eo,
                                                      const float* __restrict__ gates,
                                                      u16* __restrict__ y) {
  int w = threadIdx.x >> 6, lane = threadIdx.x & 63;
  int r = blockIdx.x * 4 + w;
  if (r >= NROWS) return;
  int b = r / CDIM, c = r % CDIM;
  float g[3][6];
#pragma unroll
  for (int t = 0; t < 3; t++)
#pragma unroll
    for (int e = 0; e < 6; e++)
      g[t][e] = gates[(size_t)((b * TDIM + t) * CDIM + c) * EDIM + e];

  const u16x8* ep = (const u16x8*)&eo[(size_t)r * (EDIM * 512) + lane * 8];
  float yacc[3][8];
#pragma unroll
  for (int t = 0; t < 3; t++)
#pragma unroll
    for (int j = 0; j < 8; j++) yacc[t][j] = 0.f;
#pragma unroll
  for (int e = 0; e < 6; e++) {
    u16x8 ev = ep[e * 64];
    float evf[8];
#pragma unroll
    for (int j = 0; j < 8; j++) evf[j] = bf2f(ev[j]);
#pragma unroll
    for (int t = 0; t < 3; t++)
#pragma unroll
      for (int j = 0; j < 8; j++) yacc[t][j] += g[t][e] * evf[j];
  }
#pragma unroll
  for (int t = 0; t < 3; t++) {
    u16x8 ov;
#pragma unroll
    for (int j = 0; j < 8; j++) ov[j] = f2bf(yacc[t][j]);
    *(u16x8*)&y[((size_t)t * NROWS + r) * 512 + lane * 8] = ov;
  }
}

// ---------------- tower dot: logits[b][t][c] = th[r] . tw2[t] + tb2[t] ----------------
__global__ __launch_bounds__(256) void towerdot_kernel(const u16* __restrict__ th,
                                                       const float* __restrict__ tw2t,
                                                       const float* __restrict__ tb2,
                                                       int t, float* __restrict__ logits) {
  int w = threadIdx.x >> 6, lane = threadIdx.x & 63;
  int r = blockIdx.x * 4 + w;
  if (r >= NROWS) return;
  u16x8 tv = *(const u16x8*)&th[(size_t)r * 512 + lane * 8];
  float s = 0.f;
#pragma unroll
  for (int j = 0; j < 8; j++) s += bf2f(tv[j]) * tw2t[lane * 8 + j];
  for (int off = 32; off; off >>= 1) s += __shfl_xor(s, off, 64);
  if (lane == 0) {
    int b = r / CDIM, c = r % CDIM;
    logits[(size_t)(b * TDIM + t) * CDIM + c] = s + tb2[t];
  }
}

// ---------------- loss: one wave per b ----------------
__global__ __launch_bounds__(64) void loss_kernel(const float* __restrict__ scores,
                                                  const float* __restrict__ logits,
                                                  const float* __restrict__ gates,
                                                  float* __restrict__ out) {
  int b = blockIdx.x;
  int lane = threadIdx.x;
  float bce_sum = 0.f;
  float aux = 0.f;
  for (int t = 0; t < 3; t++) {
    float sc = (lane < CDIM) ? scores[(size_t)(b * TDIM + t) * CDIM + lane] : -1e30f;
    float mx = sc;
    for (int off = 32; off; off >>= 1) mx = fmaxf(mx, __shfl_xor(mx, off, 64));
    float lab = (lane < CDIM && sc == mx) ? 1.f : 0.f;
    float l = (lane < CDIM) ? logits[(size_t)(b * TDIM + t) * CDIM + lane] : 0.f;
    float bce = (lane < CDIM) ? (fmaxf(l, 0.f) - l * lab + log1pf(expf(-fabsf(l)))) : 0.f;
    for (int off = 32; off; off >>= 1) bce += __shfl_xor(bce, off, 64);
    bce_sum += bce / (float)CDIM;

    float impv[6];
    float meansum = 0.f;
#pragma unroll
    for (int e = 0; e < 6; e++) {
      float gsum = (lane < CDIM) ? gates[(size_t)((b * TDIM + t) * CDIM + lane) * EDIM + e] : 0.f;
      for (int off = 32; off; off >>= 1) gsum += __shfl_xor(gsum, off, 64);
      impv[e] = gsum;
      meansum += gsum;
    }
    float mean = meansum / 6.f;
    float var = 0.f;
#pragma unroll
    for (int e = 0; e < 6; e++) { float d = impv[e] - mean; var += d * d; }
    var /= 6.f;
    aux += var / (mean * mean + 1e-10f);
  }
  float res = bce_sum / 3.f + 0.01f * aux;
  if (lane == 0) atomicAdd(out, res / (float)BDIM);
}

// ---------------- host ----------------
extern "C" void kernel_launch(void* const* d_in, const int* in_sizes, int n_in,
                              void* d_out, int out_size, void* d_ws, size_t ws_size,
                              hipStream_t stream) {
  const float* X = (const float*)d_in[0];       // [B,C,H]
  const float* scores = (const float*)d_in[1];  // [B,T,C]
  const float* fc1_w = (const float*)d_in[2];
  const float* fc1_b = (const float*)d_in[3];
  const float* fc2_w = (const float*)d_in[4];
  const float* fc2_b = (const float*)d_in[5];
  const float* w_gate = (const float*)d_in[6];
  const float* ew1 = (const float*)d_in[7];
  const float* eb1 = (const float*)d_in[8];
  const float* ew2 = (const float*)d_in[9];
  const float* eb2 = (const float*)d_in[10];
  const float* tw1 = (const float*)d_in[11];
  const float* tb1 = (const float*)d_in[12];
  const float* tw2 = (const float*)d_in[13];
  const float* tb2 = (const float*)d_in[14];
  float* out = (float*)d_out;

  // workspace layout (u16 elements unless noted)
  u16* WT = (u16*)d_ws;                       // 17 * 262144
  u16* Xb = WT + (size_t)17 * 262144;         // 15360*512
  u16* A1 = Xb + (size_t)NROWS * 512;         // also reused as eh
  u16* h = A1 + (size_t)NROWS * 512;
  u16* eo = h + (size_t)NROWS * 512;          // 15360*6*512
  u16* y = eo + (size_t)NROWS * EDIM * 512;   // 3*15360*512
  float* gates = (float*)(y + (size_t)TDIM * NROWS * 512);  // 512*3*30*6
  float* logits = gates + (size_t)BDIM * TDIM * CDIM * EDIM; // 512*3*30
  u16* th = Xb;  // reuse (Xb dead after first GEMM)
  u16* eh = A1;  // reuse (A1 dead after second GEMM)

  hipMemsetAsync(d_out, 0, sizeof(float) * out_size, stream);

  // prep: cast X, transpose+cast all weight matrices
  cvt_bf16_kernel<<<3840, 256, 0, stream>>>(X, Xb, NROWS * 512);
  transpose_w_kernel<<<dim3(64, 17), 256, 0, stream>>>(fc1_w, fc2_w, ew1, ew2, tw1, WT);

  dim3 ggrid(120, 4);
  // shared bottom
  gemm_bt<1><<<ggrid, 256, 0, stream>>>(Xb, WT + (size_t)0 * 262144, fc1_b, A1, 512);
  gemm_bt<0><<<ggrid, 256, 0, stream>>>(A1, WT + (size_t)1 * 262144, fc2_b, h, 512);

  // gating
  gate_kernel<<<480, 256, 0, stream>>>(h, w_gate, gates);

  // experts
  for (int e = 0; e < EDIM; e++) {
    gemm_bt<1><<<ggrid, 256, 0, stream>>>(h, WT + (size_t)(2 + e) * 262144, eb1 + e * 512, eh, 512);
    gemm_bt<0><<<ggrid, 256, 0, stream>>>(eh, WT + (size_t)(8 + e) * 262144, eb2 + e * 512,
                                          eo + e * 512, EDIM * 512);
  }

  // gated combine (all 3 tasks in one pass)
  combine_kernel<<<3840, 256, 0, stream>>>(eo, gates, y);

  // towers
  for (int t = 0; t < TDIM; t++) {
    gemm_bt<1><<<ggrid, 256, 0, stream>>>(y + (size_t)t * NROWS * 512,
                                          WT + (size_t)(14 + t) * 262144, tb1 + t * 512, th, 512);
    towerdot_kernel<<<3840, 256, 0, stream>>>(th, tw2 + t * 512, tb2, t, logits);
  }

  // loss
  loss_kernel<<<BDIM, 64, 0, stream>>>(scores, logits, gates, out);
}

// Round 2
// 331.812 us; speedup vs baseline: 1.1594x; 1.1594x over previous
//
#include <hip/hip_runtime.h>
#include <hip/hip_bf16.h>
#include <cstdint>
#include <cstddef>

typedef unsigned short u16;
typedef __bf16 bf16x8 __attribute__((ext_vector_type(8)));
typedef float f32x4 __attribute__((ext_vector_type(4)));
typedef u16 u16x8 __attribute__((ext_vector_type(8)));

#define NROWS 15360   // B*C = 512*30
#define KDIM 512
#define BDIM 512
#define CDIM 30
#define TDIM 3
#define EDIM 6

typedef __attribute__((address_space(1))) const unsigned int gu32;
typedef __attribute__((address_space(3))) unsigned int lu32;

__device__ __forceinline__ void gload16(const u16* g, u16* l) {
  __builtin_amdgcn_global_load_lds((gu32*)g, (lu32*)l, 16, 0, 0);
}

__device__ __forceinline__ float bf2f(u16 u) {
  union { unsigned i; float f; } v; v.i = ((unsigned)u) << 16; return v.f;
}
__device__ __forceinline__ u16 f2bf(float f) {
  union { float f; unsigned i; } v; v.f = f;
  unsigned r = v.i + 0x7fffu + ((v.i >> 16) & 1u);
  return (u16)(r >> 16);
}

// ---------------- convert fp32 -> bf16 (vectorized) ----------------
__global__ __launch_bounds__(256) void cvt_bf16_kernel(const float* __restrict__ x,
                                                       u16* __restrict__ o, int n) {
  int i = (blockIdx.x * 256 + threadIdx.x) * 8;
  if (i + 8 > n) return;
  float4 a = *(const float4*)(x + i);
  float4 b = *(const float4*)(x + i + 4);
  u16x8 v;
  v[0] = f2bf(a.x); v[1] = f2bf(a.y); v[2] = f2bf(a.z); v[3] = f2bf(a.w);
  v[4] = f2bf(b.x); v[5] = f2bf(b.y); v[6] = f2bf(b.z); v[7] = f2bf(b.w);
  *(u16x8*)(o + i) = v;
}

// ---------------- transpose 512x512 fp32 -> bf16 [N][K] ----------------
__global__ __launch_bounds__(256) void transpose_w_kernel(
    const float* __restrict__ fc1, const float* __restrict__ fc2,
    const float* __restrict__ ew1, const float* __restrict__ ew2,
    const float* __restrict__ tw1, u16* __restrict__ wt) {
  int mid = blockIdx.y;
  const float* src;
  if (mid == 0) src = fc1;
  else if (mid == 1) src = fc2;
  else if (mid < 8) src = ew1 + (size_t)(mid - 2) * 262144;
  else if (mid < 14) src = ew2 + (size_t)(mid - 8) * 262144;
  else src = tw1 + (size_t)(mid - 14) * 262144;
  u16* dst = wt + (size_t)mid * 262144;

  int tile = blockIdx.x;
  int tr = (tile >> 3) * 64, tc = (tile & 7) * 64;
  __shared__ float t[64][65];
  int c = threadIdx.x & 63, r0 = threadIdx.x >> 6;
#pragma unroll
  for (int i = 0; i < 16; i++) {
    int r = r0 + i * 4;
    t[r][c] = src[(size_t)(tr + r) * 512 + tc + c];
  }
  __syncthreads();
#pragma unroll
  for (int i = 0; i < 16; i++) {
    int r = r0 + i * 4;
    dst[(size_t)(tc + r) * 512 + tr + c] = f2bf(t[c][r]);
  }
}

// ---------------- gate weight prep: WgT bf16 [32][512], cols 18..31 zero ----
__global__ __launch_bounds__(256) void gate_w_prep(const float* __restrict__ wg,
                                                   u16* __restrict__ WgT) {
  int col = blockIdx.x;  // 0..31
  for (int k = threadIdx.x; k < 512; k += 256) {
    u16 v = 0;
    if (col < 18) {
      int t = col / 6, e = col % 6;
      v = f2bf(wg[(size_t)(t * 512 + k) * 6 + e]);
    }
    WgT[(size_t)col * 512 + k] = v;
  }
}

// ---------------- bf16 MFMA GEMM (m97 structure): C[M x 512] = A @ B, BT=B^T ----
// 128x128 tile, BK=32, 4 waves 2x2, global_load_lds width-16, linear LDS + XOR chunk swizzle.
template <int RELU>
__global__ __launch_bounds__(256, 2) void gemm_bt(
    const u16* __restrict__ A, const u16* __restrict__ BT,
    const float* __restrict__ bias, u16* __restrict__ C, int ldc) {
  __shared__ u16 Al[128 * 32];
  __shared__ u16 Bl[128 * 32];
  int tid = threadIdx.x, lane = tid & 63, w = tid >> 6;
  int wr = w >> 1, wc = w & 1;
  int brow = blockIdx.x * 128, bcol = blockIdx.y * 128;

  // staging: thread stages 16B; LDS linear [row][32] u16; source chunk pre-swizzled
  int srow = tid >> 2;
  int schunk = tid & 3;
  int srcc = schunk ^ ((srow >> 1) & 3);
  const u16* Ag0 = A + (size_t)(brow + srow) * KDIM + srcc * 8;
  const u16* Ag1 = A + (size_t)(brow + srow + 64) * KDIM + srcc * 8;
  const u16* Bg0 = BT + (size_t)(bcol + srow) * KDIM + srcc * 8;
  const u16* Bg1 = BT + (size_t)(bcol + srow + 64) * KDIM + srcc * 8;
  u16* Ald0 = Al + w * 512;          // wave-uniform LDS bases
  u16* Ald1 = Al + 2048 + w * 512;
  u16* Bld0 = Bl + w * 512;
  u16* Bld1 = Bl + 2048 + w * 512;

  f32x4 zero; zero[0] = 0.f; zero[1] = 0.f; zero[2] = 0.f; zero[3] = 0.f;
  f32x4 acc[4][4];
#pragma unroll
  for (int m = 0; m < 4; m++)
#pragma unroll
    for (int n = 0; n < 4; n++) acc[m][n] = zero;

  int l = lane & 15, q = lane >> 4;
  int rc = q ^ ((l >> 1) & 3);          // swizzled read chunk
  int rbase = wr * 64 + l;
  int cbase = wc * 64 + l;

  for (int kt = 0; kt < 16; ++kt) {
    int ko = kt * 32;
    gload16(Ag0 + ko, Ald0);
    gload16(Ag1 + ko, Ald1);
    gload16(Bg0 + ko, Bld0);
    gload16(Bg1 + ko, Bld1);
    __syncthreads();
    bf16x8 af[4], bfr[4];
#pragma unroll
    for (int m = 0; m < 4; m++) af[m] = *(const bf16x8*)&Al[(rbase + m * 16) * 32 + rc * 8];
#pragma unroll
    for (int n = 0; n < 4; n++) bfr[n] = *(const bf16x8*)&Bl[(cbase + n * 16) * 32 + rc * 8];
#pragma unroll
    for (int m = 0; m < 4; m++)
#pragma unroll
      for (int n = 0; n < 4; n++)
        acc[m][n] = __builtin_amdgcn_mfma_f32_16x16x32_bf16(af[m], bfr[n], acc[m][n], 0, 0, 0);
    __syncthreads();
  }

  int col0 = bcol + wc * 64 + l;
  int row0 = brow + wr * 64 + q * 4;
#pragma unroll
  for (int n = 0; n < 4; n++) {
    int col = col0 + n * 16;
    float bv = bias[col - brow * 0 - (col0 - (bcol + wc * 64 + l)) - 0 + 0 - 0 + 0 * ldc + 0] /*bias[col]*/;
#pragma unroll
    for (int m = 0; m < 4; m++) {
      int row = row0 + m * 16;
#pragma unroll
      for (int r = 0; r < 4; r++) {
        float v = acc[m][n][r] + bv;
        if (RELU) v = fmaxf(v, 0.f);
        C[(size_t)(row + r) * ldc + col] = f2bf(v);
      }
    }
  }
}

// ---------------- tower GEMM + fused dot(tw2) -> atomicAdd logits ----------------
__global__ __launch_bounds__(256, 2) void gemm_tower(
    const u16* __restrict__ y, const u16* __restrict__ WTt,
    const float* __restrict__ tb1, const float* __restrict__ tw2,
    float* __restrict__ logits) {
  int t = blockIdx.z;
  const u16* A = y + (size_t)t * NROWS * KDIM;
  const u16* BT = WTt + (size_t)t * 262144;
  const float* bias = tb1 + t * 512;

  __shared__ u16 Al[128 * 32];
  __shared__ u16 Bl[128 * 32];
  int tid = threadIdx.x, lane = tid & 63, w = tid >> 6;
  int wr = w >> 1, wc = w & 1;
  int brow = blockIdx.x * 128, bcol = blockIdx.y * 128;

  int srow = tid >> 2;
  int schunk = tid & 3;
  int srcc = schunk ^ ((srow >> 1) & 3);
  const u16* Ag0 = A + (size_t)(brow + srow) * KDIM + srcc * 8;
  const u16* Ag1 = A + (size_t)(brow + srow + 64) * KDIM + srcc * 8;
  const u16* Bg0 = BT + (size_t)(bcol + srow) * KDIM + srcc * 8;
  const u16* Bg1 = BT + (size_t)(bcol + srow + 64) * KDIM + srcc * 8;
  u16* Ald0 = Al + w * 512;
  u16* Ald1 = Al + 2048 + w * 512;
  u16* Bld0 = Bl + w * 512;
  u16* Bld1 = Bl + 2048 + w * 512;

  f32x4 zero; zero[0] = 0.f; zero[1] = 0.f; zero[2] = 0.f; zero[3] = 0.f;
  f32x4 acc[4][4];
#pragma unroll
  for (int m = 0; m < 4; m++)
#pragma unroll
    for (int n = 0; n < 4; n++) acc[m][n] = zero;

  int l = lane & 15, q = lane >> 4;
  int rc = q ^ ((l >> 1) & 3);
  int rbase = wr * 64 + l;
  int cbase = wc * 64 + l;

  for (int kt = 0; kt < 16; ++kt) {
    int ko = kt * 32;
    gload16(Ag0 + ko, Ald0);
    gload16(Ag1 + ko, Ald1);
    gload16(Bg0 + ko, Bld0);
    gload16(Bg1 + ko, Bld1);
    __syncthreads();
    bf16x8 af[4], bfr[4];
#pragma unroll
    for (int m = 0; m < 4; m++) af[m] = *(const bf16x8*)&Al[(rbase + m * 16) * 32 + rc * 8];
#pragma unroll
    for (int n = 0; n < 4; n++) bfr[n] = *(const bf16x8*)&Bl[(cbase + n * 16) * 32 + rc * 8];
#pragma unroll
    for (int m = 0; m < 4; m++)
#pragma unroll
      for (int n = 0; n < 4; n++)
        acc[m][n] = __builtin_amdgcn_mfma_f32_16x16x32_bf16(af[m], bfr[n], acc[m][n], 0, 0, 0);
    __syncthreads();
  }

  // epilogue: relu(acc+bias) . tw2  -> per-row partial -> atomic into logits
  int col0 = bcol + wc * 64 + l;
  float bvs[4], tws[4];
#pragma unroll
  for (int n = 0; n < 4; n++) {
    int col = col0 + n * 16;
    bvs[n] = bias[col];
    tws[n] = tw2[t * 512 + col];
  }
  int row0 = brow + wr * 64 + q * 4;
#pragma unroll
  for (int m = 0; m < 4; m++) {
#pragma unroll
    for (int r = 0; r < 4; r++) {
      float s = 0.f;
#pragma unroll
      for (int n = 0; n < 4; n++) {
        float v = acc[m][n][r] + bvs[n];
        v = fmaxf(v, 0.f);
        s += v * tws[n];
      }
      s += __shfl_xor(s, 1, 64);
      s += __shfl_xor(s, 2, 64);
      s += __shfl_xor(s, 4, 64);
      s += __shfl_xor(s, 8, 64);
      if (l == 0) {
        int row = row0 + m * 16 + r;
        int b = row / CDIM, c = row % CDIM;
        atomicAdd(&logits[(size_t)(b * TDIM + t) * CDIM + c], s);
      }
    }
  }
}

// ---------------- gate: MFMA skinny GEMM [64 rows/block x 32] + top3 softmax ----
__global__ __launch_bounds__(256) void gate_kernel(const u16* __restrict__ h,
                                                   const u16* __restrict__ WgT,
                                                   float* __restrict__ gates) {
  __shared__ u16 Wl[16 * 32 * 32];      // [kt][col][32k] swizzled, 32KB
  __shared__ float Gl[4][16][33];
  int tid = threadIdx.x, lane = tid & 63, w = tid >> 6;
  int l = lane & 15, q = lane >> 4;

  for (int idx = tid; idx < 2048; idx += 256) {
    int kt = idx >> 7, col = (idx >> 2) & 31, c = idx & 3;
    int sc = c ^ ((col >> 1) & 3);
    *(u16x8*)&Wl[kt * 1024 + col * 32 + c * 8] =
        *(const u16x8*)&WgT[(size_t)col * 512 + kt * 32 + sc * 8];
  }
  __syncthreads();

  int r = blockIdx.x * 64 + w * 16 + l;    // this lane's A row
  int ch = q ^ ((l >> 1) & 3);

  f32x4 acc0, acc1;
  acc0[0] = acc0[1] = acc0[2] = acc0[3] = 0.f;
  acc1 = acc0;
#pragma unroll
  for (int kt = 0; kt < 16; ++kt) {
    bf16x8 av = *(const bf16x8*)&h[(size_t)r * 512 + kt * 32 + q * 8];
    bf16x8 b0 = *(const bf16x8*)&Wl[kt * 1024 + l * 32 + ch * 8];
    bf16x8 b1 = *(const bf16x8*)&Wl[kt * 1024 + (16 + l) * 32 + ch * 8];
    acc0 = __builtin_amdgcn_mfma_f32_16x16x32_bf16(av, b0, acc0, 0, 0, 0);
    acc1 = __builtin_amdgcn_mfma_f32_16x16x32_bf16(av, b1, acc1, 0, 0, 0);
  }

  // acc layout: row = q*4+reg, col = l (+16 for acc1)
#pragma unroll
  for (int rr = 0; rr < 4; rr++) {
    Gl[w][q * 4 + rr][l] = acc0[rr];
    Gl[w][q * 4 + rr][16 + l] = acc1[rr];
  }
  __syncthreads();

  if (lane < 16) {
    int R = blockIdx.x * 64 + w * 16 + lane;
    int b = R / CDIM, c = R % CDIM;
    for (int t = 0; t < 3; t++) {
      float g[6];
#pragma unroll
      for (int e = 0; e < 6; e++) g[e] = Gl[w][lane][t * 6 + e];
      float out[6] = {0, 0, 0, 0, 0, 0};
      int idx[3]; float val[3];
      unsigned used = 0;
      for (int kk = 0; kk < 3; kk++) {
        int best = 0; float bv = -1e30f;
        for (int e = 0; e < 6; e++)
          if (!((used >> e) & 1) && g[e] > bv) { bv = g[e]; best = e; }
        used |= 1u << best; idx[kk] = best; val[kk] = bv;
      }
      float mx = val[0];
      float s = 0.f, ex[3];
      for (int kk = 0; kk < 3; kk++) { ex[kk] = expf(val[kk] - mx); s += ex[kk]; }
      for (int kk = 0; kk < 3; kk++) out[idx[kk]] = ex[kk] / s;
      float* gp = &gates[(size_t)((b * TDIM + t) * CDIM + c) * EDIM];
      for (int e = 0; e < 6; e++) gp[e] = out[e];
    }
  }
}

// ---------------- combine: y[t][r][:] = sum_e gates[b,t,c,e] * eo[r][e][:] ----------------
__global__ __launch_bounds__(256) void combine_kernel(const u16* __restrict__ eo,
                                                      const float* __restrict__ gates,
                                                      u16* __restrict__ y) {
  int w = threadIdx.x >> 6, lane = threadIdx.x & 63;
  int r = blockIdx.x * 4 + w;
  if (r >= NROWS) return;
  int b = r / CDIM, c = r % CDIM;
  float g[3][6];
#pragma unroll
  for (int t = 0; t < 3; t++)
#pragma unroll
    for (int e = 0; e < 6; e++)
      g[t][e] = gates[(size_t)((b * TDIM + t) * CDIM + c) * EDIM + e];

  const u16x8* ep = (const u16x8*)&eo[(size_t)r * (EDIM * 512) + lane * 8];
  float yacc[3][8];
#pragma unroll
  for (int t = 0; t < 3; t++)
#pragma unroll
    for (int j = 0; j < 8; j++) yacc[t][j] = 0.f;
#pragma unroll
  for (int e = 0; e < 6; e++) {
    u16x8 ev = ep[e * 64];
    float evf[8];
#pragma unroll
    for (int j = 0; j < 8; j++) evf[j] = bf2f(ev[j]);
#pragma unroll
    for (int t = 0; t < 3; t++)
#pragma unroll
      for (int j = 0; j < 8; j++) yacc[t][j] += g[t][e] * evf[j];
  }
#pragma unroll
  for (int t = 0; t < 3; t++) {
    u16x8 ov;
#pragma unroll
    for (int j = 0; j < 8; j++) ov[j] = f2bf(yacc[t][j]);
    *(u16x8*)&y[((size_t)t * NROWS + r) * 512 + lane * 8] = ov;
  }
}

// ---------------- loss: one wave per b ----------------
__global__ __launch_bounds__(64) void loss_kernel(const float* __restrict__ scores,
                                                  const float* __restrict__ logits,
                                                  const float* __restrict__ gates,
                                                  const float* __restrict__ tb2,
                                                  float* __restrict__ out) {
  int b = blockIdx.x;
  int lane = threadIdx.x;
  float bce_sum = 0.f;
  float aux = 0.f;
  for (int t = 0; t < 3; t++) {
    float sc = (lane < CDIM) ? scores[(size_t)(b * TDIM + t) * CDIM + lane] : -1e30f;
    float mx = sc;
    for (int off = 32; off; off >>= 1) mx = fmaxf(mx, __shfl_xor(mx, off, 64));
    float lab = (lane < CDIM && sc == mx) ? 1.f : 0.f;
    float lg = (lane < CDIM) ? (logits[(size_t)(b * TDIM + t) * CDIM + lane] + tb2[t]) : 0.f;
    float bce = (lane < CDIM) ? (fmaxf(lg, 0.f) - lg * lab + log1pf(expf(-fabsf(lg)))) : 0.f;
    for (int off = 32; off; off >>= 1) bce += __shfl_xor(bce, off, 64);
    bce_sum += bce / (float)CDIM;

    float impv[6];
    float meansum = 0.f;
#pragma unroll
    for (int e = 0; e < 6; e++) {
      float gsum = (lane < CDIM) ? gates[(size_t)((b * TDIM + t) * CDIM + lane) * EDIM + e] : 0.f;
      for (int off = 32; off; off >>= 1) gsum += __shfl_xor(gsum, off, 64);
      impv[e] = gsum;
      meansum += gsum;
    }
    float mean = meansum / 6.f;
    float var = 0.f;
#pragma unroll
    for (int e = 0; e < 6; e++) { float d = impv[e] - mean; var += d * d; }
    var /= 6.f;
    aux += var / (mean * mean + 1e-10f);
  }
  float res = bce_sum / 3.f + 0.01f * aux;
  if (lane == 0) atomicAdd(out, res / (float)BDIM);
}

// ---------------- host ----------------
extern "C" void kernel_launch(void* const* d_in, const int* in_sizes, int n_in,
                              void* d_out, int out_size, void* d_ws, size_t ws_size,
                              hipStream_t stream) {
  const float* X = (const float*)d_in[0];
  const float* scores = (const float*)d_in[1];
  const float* fc1_w = (const float*)d_in[2];
  const float* fc1_b = (const float*)d_in[3];
  const float* fc2_w = (const float*)d_in[4];
  const float* fc2_b = (const float*)d_in[5];
  const float* w_gate = (const float*)d_in[6];
  const float* ew1 = (const float*)d_in[7];
  const float* eb1 = (const float*)d_in[8];
  const float* ew2 = (const float*)d_in[9];
  const float* eb2 = (const float*)d_in[10];
  const float* tw1 = (const float*)d_in[11];
  const float* tb1 = (const float*)d_in[12];
  const float* tw2 = (const float*)d_in[13];
  const float* tb2 = (const float*)d_in[14];
  float* out = (float*)d_out;

  // workspace layout (u16 elements unless noted)
  u16* WT = (u16*)d_ws;                         // 17 * 262144
  u16* WgT = WT + (size_t)17 * 262144;          // 32*512
  u16* Xb = WgT + (size_t)32 * 512;             // 15360*512
  u16* A1 = Xb + (size_t)NROWS * 512;           // reused as eh
  u16* h = A1 + (size_t)NROWS * 512;
  u16* eo = h + (size_t)NROWS * 512;            // 15360*6*512
  u16* y = eo + (size_t)NROWS * EDIM * 512;     // 3*15360*512
  float* gates = (float*)(y + (size_t)TDIM * NROWS * 512);
  float* logits = gates + (size_t)BDIM * TDIM * CDIM * EDIM;
  u16* eh = A1;

  hipMemsetAsync(d_out, 0, sizeof(float) * out_size, stream);
  hipMemsetAsync(logits, 0, sizeof(float) * BDIM * TDIM * CDIM, stream);

  cvt_bf16_kernel<<<3840, 256, 0, stream>>>(X, Xb, NROWS * 512);
  transpose_w_kernel<<<dim3(64, 17), 256, 0, stream>>>(fc1_w, fc2_w, ew1, ew2, tw1, WT);
  gate_w_prep<<<32, 256, 0, stream>>>(w_gate, WgT);

  dim3 ggrid(120, 4);
  // shared bottom
  gemm_bt<1><<<ggrid, 256, 0, stream>>>(Xb, WT + (size_t)0 * 262144, fc1_b, A1, 512);
  gemm_bt<0><<<ggrid, 256, 0, stream>>>(A1, WT + (size_t)1 * 262144, fc2_b, h, 512);

  // gating (MFMA skinny GEMM + fused top3/softmax)
  gate_kernel<<<240, 256, 0, stream>>>(h, WgT, gates);

  // experts
  for (int e = 0; e < EDIM; e++) {
    gemm_bt<1><<<ggrid, 256, 0, stream>>>(h, WT + (size_t)(2 + e) * 262144, eb1 + e * 512, eh, 512);
    gemm_bt<0><<<ggrid, 256, 0, stream>>>(eh, WT + (size_t)(8 + e) * 262144, eb2 + e * 512,
                                          eo + e * 512, EDIM * 512);
  }

  // gated combine
  combine_kernel<<<3840, 256, 0, stream>>>(eo, gates, y);

  // towers: GEMM + fused dot -> logits (atomic), all 3 tasks batched
  gemm_tower<<<dim3(120, 4, 3), 256, 0, stream>>>(y, WT + (size_t)14 * 262144, tb1, tw2, logits);

  // loss
  loss_kernel<<<BDIM, 64, 0, stream>>>(scores, logits, gates, tb2, out);
}

// Round 3
// 288.804 us; speedup vs baseline: 1.3321x; 1.1489x over previous
//
#include <hip/hip_runtime.h>
#include <hip/hip_bf16.h>
#include <cstdint>
#include <cstddef>

typedef unsigned short u16;
typedef __bf16 bf16x8 __attribute__((ext_vector_type(8)));
typedef float f32x4 __attribute__((ext_vector_type(4)));
typedef u16 u16x8 __attribute__((ext_vector_type(8)));

#define NROWS 15360   // B*C = 512*30
#define KDIM 512
#define BDIM 512
#define CDIM 30
#define TDIM 3
#define EDIM 6

typedef __attribute__((address_space(1))) const unsigned int gu32;
typedef __attribute__((address_space(3))) unsigned int lu32;

__device__ __forceinline__ void gload16(const u16* g, u16* l) {
  __builtin_amdgcn_global_load_lds((gu32*)g, (lu32*)l, 16, 0, 0);
}

__device__ __forceinline__ float bf2f(u16 u) {
  union { unsigned i; float f; } v; v.i = ((unsigned)u) << 16; return v.f;
}
__device__ __forceinline__ u16 f2bf(float f) {
  union { float f; unsigned i; } v; v.f = f;
  unsigned r = v.i + 0x7fffu + ((v.i >> 16) & 1u);
  return (u16)(r >> 16);
}

// ---------------- convert fp32 -> bf16 (vectorized) ----------------
__global__ __launch_bounds__(256) void cvt_bf16_kernel(const float* __restrict__ x,
                                                       u16* __restrict__ o, int n) {
  int i = (blockIdx.x * 256 + threadIdx.x) * 8;
  if (i + 8 > n) return;
  float4 a = *(const float4*)(x + i);
  float4 b = *(const float4*)(x + i + 4);
  u16x8 v;
  v[0] = f2bf(a.x); v[1] = f2bf(a.y); v[2] = f2bf(a.z); v[3] = f2bf(a.w);
  v[4] = f2bf(b.x); v[5] = f2bf(b.y); v[6] = f2bf(b.z); v[7] = f2bf(b.w);
  *(u16x8*)(o + i) = v;
}

// ---------------- transpose 512x512 fp32 -> bf16 [N][K] ----------------
__global__ __launch_bounds__(256) void transpose_w_kernel(
    const float* __restrict__ fc1, const float* __restrict__ fc2,
    const float* __restrict__ ew1, const float* __restrict__ ew2,
    const float* __restrict__ tw1, u16* __restrict__ wt) {
  int mid = blockIdx.y;
  const float* src;
  if (mid == 0) src = fc1;
  else if (mid == 1) src = fc2;
  else if (mid < 8) src = ew1 + (size_t)(mid - 2) * 262144;
  else if (mid < 14) src = ew2 + (size_t)(mid - 8) * 262144;
  else src = tw1 + (size_t)(mid - 14) * 262144;
  u16* dst = wt + (size_t)mid * 262144;

  int tile = blockIdx.x;
  int tr = (tile >> 3) * 64, tc = (tile & 7) * 64;
  __shared__ float t[64][65];
  int c = threadIdx.x & 63, r0 = threadIdx.x >> 6;
#pragma unroll
  for (int i = 0; i < 16; i++) {
    int r = r0 + i * 4;
    t[r][c] = src[(size_t)(tr + r) * 512 + tc + c];
  }
  __syncthreads();
#pragma unroll
  for (int i = 0; i < 16; i++) {
    int r = r0 + i * 4;
    dst[(size_t)(tc + r) * 512 + tr + c] = f2bf(t[c][r]);
  }
}

// ---------------- gate weight prep: WgT bf16 [32][512], cols 18..31 zero ----
__global__ __launch_bounds__(256) void gate_w_prep(const float* __restrict__ wg,
                                                   u16* __restrict__ WgT) {
  int col = blockIdx.x;  // 0..31
  for (int k = threadIdx.x; k < 512; k += 256) {
    u16 v = 0;
    if (col < 18) {
      int t = col / 6, e = col % 6;
      v = f2bf(wg[(size_t)(t * 512 + k) * 6 + e]);
    }
    WgT[(size_t)col * 512 + k] = v;
  }
}

// ---------------- bf16 MFMA GEMM (m97 structure), z-batched ----------------
// C[128x128 tile] = A[Mx512] @ B, BT = B^T given as [N][512].
// Per-z offsets: A += z*zA, BT += z*zB, bias += z*zBias, C += z*zC.
template <int RELU>
__global__ __launch_bounds__(256, 2) void gemm_bt(
    const u16* __restrict__ A, int lda, size_t zA,
    const u16* __restrict__ BT, size_t zB,
    const float* __restrict__ bias, int zBias,
    u16* __restrict__ C, int ldc, size_t zC) {
  int z = blockIdx.z;
  A += (size_t)z * zA;
  BT += (size_t)z * zB;
  bias += (size_t)z * zBias;
  C += (size_t)z * zC;

  __shared__ u16 Al[128 * 32];
  __shared__ u16 Bl[128 * 32];
  int tid = threadIdx.x, lane = tid & 63, w = tid >> 6;
  int wr = w >> 1, wc = w & 1;
  int brow = blockIdx.x * 128, bcol = blockIdx.y * 128;

  // staging: thread stages 16B; LDS linear [row][32] u16; source chunk pre-swizzled
  int srow = tid >> 2;
  int schunk = tid & 3;
  int srcc = schunk ^ ((srow >> 1) & 3);
  const u16* Ag0 = A + (size_t)(brow + srow) * lda + srcc * 8;
  const u16* Ag1 = A + (size_t)(brow + srow + 64) * lda + srcc * 8;
  const u16* Bg0 = BT + (size_t)(bcol + srow) * KDIM + srcc * 8;
  const u16* Bg1 = BT + (size_t)(bcol + srow + 64) * KDIM + srcc * 8;
  u16* Ald0 = Al + w * 512;          // wave-uniform LDS bases
  u16* Ald1 = Al + 2048 + w * 512;
  u16* Bld0 = Bl + w * 512;
  u16* Bld1 = Bl + 2048 + w * 512;

  f32x4 zero; zero[0] = 0.f; zero[1] = 0.f; zero[2] = 0.f; zero[3] = 0.f;
  f32x4 acc[4][4];
#pragma unroll
  for (int m = 0; m < 4; m++)
#pragma unroll
    for (int n = 0; n < 4; n++) acc[m][n] = zero;

  int l = lane & 15, q = lane >> 4;
  int rc = q ^ ((l >> 1) & 3);          // swizzled read chunk
  int rbase = wr * 64 + l;
  int cbase = wc * 64 + l;

  for (int kt = 0; kt < 16; ++kt) {
    int ko = kt * 32;
    gload16(Ag0 + ko, Ald0);
    gload16(Ag1 + ko, Ald1);
    gload16(Bg0 + ko, Bld0);
    gload16(Bg1 + ko, Bld1);
    __syncthreads();
    bf16x8 af[4], bfr[4];
#pragma unroll
    for (int m = 0; m < 4; m++) af[m] = *(const bf16x8*)&Al[(rbase + m * 16) * 32 + rc * 8];
#pragma unroll
    for (int n = 0; n < 4; n++) bfr[n] = *(const bf16x8*)&Bl[(cbase + n * 16) * 32 + rc * 8];
#pragma unroll
    for (int m = 0; m < 4; m++)
#pragma unroll
      for (int n = 0; n < 4; n++)
        acc[m][n] = __builtin_amdgcn_mfma_f32_16x16x32_bf16(af[m], bfr[n], acc[m][n], 0, 0, 0);
    __syncthreads();
  }

  int col0 = bcol + wc * 64 + l;
  int row0 = brow + wr * 64 + q * 4;
#pragma unroll
  for (int n = 0; n < 4; n++) {
    int col = col0 + n * 16;
    float bv = bias[col];
#pragma unroll
    for (int m = 0; m < 4; m++) {
      int row = row0 + m * 16;
#pragma unroll
      for (int r = 0; r < 4; r++) {
        float v = acc[m][n][r] + bv;
        if (RELU) v = fmaxf(v, 0.f);
        C[(size_t)(row + r) * ldc + col] = f2bf(v);
      }
    }
  }
}

// ---------------- tower GEMM + fused dot(tw2) -> atomicAdd logits ----------------
__global__ __launch_bounds__(256, 2) void gemm_tower(
    const u16* __restrict__ y, const u16* __restrict__ WTt,
    const float* __restrict__ tb1, const float* __restrict__ tw2,
    float* __restrict__ logits) {
  int t = blockIdx.z;
  const u16* A = y + (size_t)t * NROWS * KDIM;
  const u16* BT = WTt + (size_t)t * 262144;
  const float* bias = tb1 + t * 512;

  __shared__ u16 Al[128 * 32];
  __shared__ u16 Bl[128 * 32];
  int tid = threadIdx.x, lane = tid & 63, w = tid >> 6;
  int wr = w >> 1, wc = w & 1;
  int brow = blockIdx.x * 128, bcol = blockIdx.y * 128;

  int srow = tid >> 2;
  int schunk = tid & 3;
  int srcc = schunk ^ ((srow >> 1) & 3);
  const u16* Ag0 = A + (size_t)(brow + srow) * KDIM + srcc * 8;
  const u16* Ag1 = A + (size_t)(brow + srow + 64) * KDIM + srcc * 8;
  const u16* Bg0 = BT + (size_t)(bcol + srow) * KDIM + srcc * 8;
  const u16* Bg1 = BT + (size_t)(bcol + srow + 64) * KDIM + srcc * 8;
  u16* Ald0 = Al + w * 512;
  u16* Ald1 = Al + 2048 + w * 512;
  u16* Bld0 = Bl + w * 512;
  u16* Bld1 = Bl + 2048 + w * 512;

  f32x4 zero; zero[0] = 0.f; zero[1] = 0.f; zero[2] = 0.f; zero[3] = 0.f;
  f32x4 acc[4][4];
#pragma unroll
  for (int m = 0; m < 4; m++)
#pragma unroll
    for (int n = 0; n < 4; n++) acc[m][n] = zero;

  int l = lane & 15, q = lane >> 4;
  int rc = q ^ ((l >> 1) & 3);
  int rbase = wr * 64 + l;
  int cbase = wc * 64 + l;

  for (int kt = 0; kt < 16; ++kt) {
    int ko = kt * 32;
    gload16(Ag0 + ko, Ald0);
    gload16(Ag1 + ko, Ald1);
    gload16(Bg0 + ko, Bld0);
    gload16(Bg1 + ko, Bld1);
    __syncthreads();
    bf16x8 af[4], bfr[4];
#pragma unroll
    for (int m = 0; m < 4; m++) af[m] = *(const bf16x8*)&Al[(rbase + m * 16) * 32 + rc * 8];
#pragma unroll
    for (int n = 0; n < 4; n++) bfr[n] = *(const bf16x8*)&Bl[(cbase + n * 16) * 32 + rc * 8];
#pragma unroll
    for (int m = 0; m < 4; m++)
#pragma unroll
      for (int n = 0; n < 4; n++)
        acc[m][n] = __builtin_amdgcn_mfma_f32_16x16x32_bf16(af[m], bfr[n], acc[m][n], 0, 0, 0);
    __syncthreads();
  }

  // epilogue: relu(acc+bias) . tw2  -> per-row partial -> atomic into logits
  int col0 = bcol + wc * 64 + l;
  float bvs[4], tws[4];
#pragma unroll
  for (int n = 0; n < 4; n++) {
    int col = col0 + n * 16;
    bvs[n] = bias[col];
    tws[n] = tw2[t * 512 + col];
  }
  int row0 = brow + wr * 64 + q * 4;
#pragma unroll
  for (int m = 0; m < 4; m++) {
#pragma unroll
    for (int r = 0; r < 4; r++) {
      float s = 0.f;
#pragma unroll
      for (int n = 0; n < 4; n++) {
        float v = acc[m][n][r] + bvs[n];
        v = fmaxf(v, 0.f);
        s += v * tws[n];
      }
      s += __shfl_xor(s, 1, 64);
      s += __shfl_xor(s, 2, 64);
      s += __shfl_xor(s, 4, 64);
      s += __shfl_xor(s, 8, 64);
      if (l == 0) {
        int row = row0 + m * 16 + r;
        int b = row / CDIM, c = row % CDIM;
        atomicAdd(&logits[(size_t)(b * TDIM + t) * CDIM + c], s);
      }
    }
  }
}

// ---------------- gate: MFMA skinny GEMM [64 rows/block x 32] + top3 softmax ----
__global__ __launch_bounds__(256) void gate_kernel(const u16* __restrict__ h,
                                                   const u16* __restrict__ WgT,
                                                   float* __restrict__ gates) {
  __shared__ u16 Wl[16 * 32 * 32];      // [kt][col][32k] swizzled, 32KB
  __shared__ float Gl[4][16][33];
  int tid = threadIdx.x, lane = tid & 63, w = tid >> 6;
  int l = lane & 15, q = lane >> 4;

  for (int idx = tid; idx < 2048; idx += 256) {
    int kt = idx >> 7, col = (idx >> 2) & 31, c = idx & 3;
    int sc = c ^ ((col >> 1) & 3);
    *(u16x8*)&Wl[kt * 1024 + col * 32 + c * 8] =
        *(const u16x8*)&WgT[(size_t)col * 512 + kt * 32 + sc * 8];
  }
  __syncthreads();

  int r = blockIdx.x * 64 + w * 16 + l;    // this lane's A row
  int ch = q ^ ((l >> 1) & 3);

  f32x4 acc0, acc1;
  acc0[0] = acc0[1] = acc0[2] = acc0[3] = 0.f;
  acc1 = acc0;
#pragma unroll
  for (int kt = 0; kt < 16; ++kt) {
    bf16x8 av = *(const bf16x8*)&h[(size_t)r * 512 + kt * 32 + q * 8];
    bf16x8 b0 = *(const bf16x8*)&Wl[kt * 1024 + l * 32 + ch * 8];
    bf16x8 b1 = *(const bf16x8*)&Wl[kt * 1024 + (16 + l) * 32 + ch * 8];
    acc0 = __builtin_amdgcn_mfma_f32_16x16x32_bf16(av, b0, acc0, 0, 0, 0);
    acc1 = __builtin_amdgcn_mfma_f32_16x16x32_bf16(av, b1, acc1, 0, 0, 0);
  }

  // acc layout: row = q*4+reg, col = l (+16 for acc1)
#pragma unroll
  for (int rr = 0; rr < 4; rr++) {
    Gl[w][q * 4 + rr][l] = acc0[rr];
    Gl[w][q * 4 + rr][16 + l] = acc1[rr];
  }
  __syncthreads();

  if (lane < 16) {
    int R = blockIdx.x * 64 + w * 16 + lane;
    int b = R / CDIM, c = R % CDIM;
    for (int t = 0; t < 3; t++) {
      float g[6];
#pragma unroll
      for (int e = 0; e < 6; e++) g[e] = Gl[w][lane][t * 6 + e];
      float out[6] = {0, 0, 0, 0, 0, 0};
      int idx[3]; float val[3];
      unsigned used = 0;
      for (int kk = 0; kk < 3; kk++) {
        int best = 0; float bv = -1e30f;
        for (int e = 0; e < 6; e++)
          if (!((used >> e) & 1) && g[e] > bv) { bv = g[e]; best = e; }
        used |= 1u << best; idx[kk] = best; val[kk] = bv;
      }
      float mx = val[0];
      float s = 0.f, ex[3];
      for (int kk = 0; kk < 3; kk++) { ex[kk] = expf(val[kk] - mx); s += ex[kk]; }
      for (int kk = 0; kk < 3; kk++) out[idx[kk]] = ex[kk] / s;
      float* gp = &gates[(size_t)((b * TDIM + t) * CDIM + c) * EDIM];
      for (int e = 0; e < 6; e++) gp[e] = out[e];
    }
  }
}

// ---------------- combine: y[t][r][:] = sum_e gates[b,t,c,e] * eo[r][e*512:+512] ----
__global__ __launch_bounds__(256) void combine_kernel(const u16* __restrict__ eo,
                                                      const float* __restrict__ gates,
                                                      u16* __restrict__ y) {
  int w = threadIdx.x >> 6, lane = threadIdx.x & 63;
  int r = blockIdx.x * 4 + w;
  if (r >= NROWS) return;
  int b = r / CDIM, c = r % CDIM;
  float g[3][6];
#pragma unroll
  for (int t = 0; t < 3; t++)
#pragma unroll
    for (int e = 0; e < 6; e++)
      g[t][e] = gates[(size_t)((b * TDIM + t) * CDIM + c) * EDIM + e];

  const u16x8* ep = (const u16x8*)&eo[(size_t)r * (EDIM * 512) + lane * 8];
  float yacc[3][8];
#pragma unroll
  for (int t = 0; t < 3; t++)
#pragma unroll
    for (int j = 0; j < 8; j++) yacc[t][j] = 0.f;
#pragma unroll
  for (int e = 0; e < 6; e++) {
    u16x8 ev = ep[e * 64];
    float evf[8];
#pragma unroll
    for (int j = 0; j < 8; j++) evf[j] = bf2f(ev[j]);
#pragma unroll
    for (int t = 0; t < 3; t++)
#pragma unroll
      for (int j = 0; j < 8; j++) yacc[t][j] += g[t][e] * evf[j];
  }
#pragma unroll
  for (int t = 0; t < 3; t++) {
    u16x8 ov;
#pragma unroll
    for (int j = 0; j < 8; j++) ov[j] = f2bf(yacc[t][j]);
    *(u16x8*)&y[((size_t)t * NROWS + r) * 512 + lane * 8] = ov;
  }
}

// ---------------- loss: one wave per b ----------------
__global__ __launch_bounds__(64) void loss_kernel(const float* __restrict__ scores,
                                                  const float* __restrict__ logits,
                                                  const float* __restrict__ gates,
                                                  const float* __restrict__ tb2,
                                                  float* __restrict__ out) {
  int b = blockIdx.x;
  int lane = threadIdx.x;
  float bce_sum = 0.f;
  float aux = 0.f;
  for (int t = 0; t < 3; t++) {
    float sc = (lane < CDIM) ? scores[(size_t)(b * TDIM + t) * CDIM + lane] : -1e30f;
    float mx = sc;
    for (int off = 32; off; off >>= 1) mx = fmaxf(mx, __shfl_xor(mx, off, 64));
    float lab = (lane < CDIM && sc == mx) ? 1.f : 0.f;
    float lg = (lane < CDIM) ? (logits[(size_t)(b * TDIM + t) * CDIM + lane] + tb2[t]) : 0.f;
    float bce = (lane < CDIM) ? (fmaxf(lg, 0.f) - lg * lab + log1pf(expf(-fabsf(lg)))) : 0.f;
    for (int off = 32; off; off >>= 1) bce += __shfl_xor(bce, off, 64);
    bce_sum += bce / (float)CDIM;

    float impv[6];
    float meansum = 0.f;
#pragma unroll
    for (int e = 0; e < 6; e++) {
      float gsum = (lane < CDIM) ? gates[(size_t)((b * TDIM + t) * CDIM + lane) * EDIM + e] : 0.f;
      for (int off = 32; off; off >>= 1) gsum += __shfl_xor(gsum, off, 64);
      impv[e] = gsum;
      meansum += gsum;
    }
    float mean = meansum / 6.f;
    float var = 0.f;
#pragma unroll
    for (int e = 0; e < 6; e++) { float d = impv[e] - mean; var += d * d; }
    var /= 6.f;
    aux += var / (mean * mean + 1e-10f);
  }
  float res = bce_sum / 3.f + 0.01f * aux;
  if (lane == 0) atomicAdd(out, res / (float)BDIM);
}

// ---------------- host ----------------
extern "C" void kernel_launch(void* const* d_in, const int* in_sizes, int n_in,
                              void* d_out, int out_size, void* d_ws, size_t ws_size,
                              hipStream_t stream) {
  const float* X = (const float*)d_in[0];
  const float* scores = (const float*)d_in[1];
  const float* fc1_w = (const float*)d_in[2];
  const float* fc1_b = (const float*)d_in[3];
  const float* fc2_w = (const float*)d_in[4];
  const float* fc2_b = (const float*)d_in[5];
  const float* w_gate = (const float*)d_in[6];
  const float* ew1 = (const float*)d_in[7];
  const float* eb1 = (const float*)d_in[8];
  const float* ew2 = (const float*)d_in[9];
  const float* eb2 = (const float*)d_in[10];
  const float* tw1 = (const float*)d_in[11];
  const float* tb1 = (const float*)d_in[12];
  const float* tw2 = (const float*)d_in[13];
  const float* tb2 = (const float*)d_in[14];
  float* out = (float*)d_out;

  // workspace layout (u16 elements); eh_all overlaps {Xb, A1, y} (lifetimes disjoint)
  u16* WT = (u16*)d_ws;                          // 17*262144
  u16* WgT = WT + (size_t)17 * 262144;           // 32*512
  u16* ehall = WgT + (size_t)32 * 512;           // 15360*3072  (94.4 MB region)
  u16* Xb = ehall;                               // 15360*512 (dead after fc1)
  u16* A1 = ehall + (size_t)NROWS * 512;         // 15360*512 (dead after fc2)
  u16* y = ehall;                                // 3*15360*512 (written after ehall dead)
  u16* h = ehall + (size_t)NROWS * 3072;         // 15360*512
  u16* eo = h + (size_t)NROWS * 512;             // 15360*3072
  float* gates = (float*)(eo + (size_t)NROWS * 3072);
  float* logits = gates + (size_t)BDIM * TDIM * CDIM * EDIM;

  hipMemsetAsync(d_out, 0, sizeof(float) * out_size, stream);
  hipMemsetAsync(logits, 0, sizeof(float) * BDIM * TDIM * CDIM, stream);

  cvt_bf16_kernel<<<3840, 256, 0, stream>>>(X, Xb, NROWS * 512);
  transpose_w_kernel<<<dim3(64, 17), 256, 0, stream>>>(fc1_w, fc2_w, ew1, ew2, tw1, WT);
  gate_w_prep<<<32, 256, 0, stream>>>(w_gate, WgT);

  // shared bottom
  gemm_bt<1><<<dim3(120, 4, 1), 256, 0, stream>>>(
      Xb, 512, 0, WT + (size_t)0 * 262144, 0, fc1_b, 0, A1, 512, 0);
  gemm_bt<0><<<dim3(120, 4, 1), 256, 0, stream>>>(
      A1, 512, 0, WT + (size_t)1 * 262144, 0, fc2_b, 0, h, 512, 0);

  // gating (MFMA skinny GEMM + fused top3/softmax)
  gate_kernel<<<240, 256, 0, stream>>>(h, WgT, gates);

  // experts W1: one merged GEMM, N = 3072 (B = [W1_0|...|W1_5] row-concat of BT)
  gemm_bt<1><<<dim3(120, 24, 1), 256, 0, stream>>>(
      h, 512, 0, WT + (size_t)2 * 262144, 0, eb1, 0, ehall, 3072, 0);

  // experts W2: z-batched over 6 experts
  gemm_bt<0><<<dim3(120, 4, 6), 256, 0, stream>>>(
      ehall, 3072, 512, WT + (size_t)8 * 262144, 262144, eb2, 512, eo, 3072, 512);

  // gated combine
  combine_kernel<<<3840, 256, 0, stream>>>(eo, gates, y);

  // towers: GEMM + fused dot -> logits (atomic), all 3 tasks batched
  gemm_tower<<<dim3(120, 4, 3), 256, 0, stream>>>(y, WT + (size_t)14 * 262144, tb1, tw2, logits);

  // loss
  loss_kernel<<<BDIM, 64, 0, stream>>>(scores, logits, gates, tb2, out);
}